// Round 2
// 602.247 us; speedup vs baseline: 1.0023x; 1.0023x over previous
//
#include <hip/hip_runtime.h>
#include <math.h>

#define BATCH 32
#define CHAN  512
#define HW    4096
#define KSEL  256
#define NBC   (BATCH * CHAN)   // 16384

typedef float float4v __attribute__((ext_vector_type(4)));

// ---------------------------------------------------------------------------
// Kernel 1: cosine similarity, ONE WAVE per (b,c) tile.
// 4 waves / block of 256 -> 4096 blocks. Each lane reads 16 float4 of x and y
// (whole 16 KB tile per wave), shuffle-xor reduce, lane 0 writes sims[bc].
// x loaded normally (we WANT it resident in L3 for the scale pass);
// y loaded nontemporal (streamed once -> don't evict x from L3).
// ---------------------------------------------------------------------------
__global__ __launch_bounds__(256) void sim_kernel(const float* __restrict__ x,
                                                  const float* __restrict__ y,
                                                  float* __restrict__ sims) {
    const int lane = threadIdx.x & 63;
    const int bc   = blockIdx.x * 4 + (threadIdx.x >> 6);

    const float4v* xp = (const float4v*)(x + (size_t)bc * HW);
    const float4v* yp = (const float4v*)(y + (size_t)bc * HW);

    float dot = 0.f, xx = 0.f, yy = 0.f;
    #pragma unroll
    for (int k = 0; k < HW / 4 / 64; ++k) {          // 16 float4 per lane
        float4v a = xp[lane + k * 64];
        float4v b = __builtin_nontemporal_load(yp + lane + k * 64);
        dot += a.x * b.x + a.y * b.y + a.z * b.z + a.w * b.w;
        xx  += a.x * a.x + a.y * a.y + a.z * a.z + a.w * a.w;
        yy  += b.x * b.x + b.y * b.y + b.z * b.z + b.w * b.w;
    }

    #pragma unroll
    for (int off = 32; off; off >>= 1) {
        dot += __shfl_xor(dot, off);
        xx  += __shfl_xor(xx,  off);
        yy  += __shfl_xor(yy,  off);
    }

    if (lane == 0) {
        const float nx = sqrtf(xx), ny = sqrtf(yy);
        sims[bc] = dot / (fmaxf(nx, 1e-8f) * fmaxf(ny, 1e-8f));
    }
}

// ---------------------------------------------------------------------------
// Kernel 2: per-batch exact K-smallest selection + softmax -> sparse gate.
// One block per batch, 512 threads (one per channel). O(C^2) rank in LDS with
// jax.lax.top_k tie-break semantics (among equal values, lower index first).
// ---------------------------------------------------------------------------
__global__ __launch_bounds__(512) void gate_kernel(const float* __restrict__ sims,
                                                   float* __restrict__ gate) {
    const int b = blockIdx.x;
    const int c = threadIdx.x;

    __shared__ float sv[CHAN];
    const float v = sims[b * CHAN + c];
    sv[c] = v;
    __syncthreads();

    int rank = 0;
    for (int j = 0; j < CHAN; ++j) {
        float w = sv[j];
        rank += (w < v) || (w == v && j < c);
    }
    const bool sel = rank < KSEL;

    __shared__ float red[CHAN];
    red[c] = sel ? v : -INFINITY;
    __syncthreads();
    #pragma unroll
    for (int s = CHAN / 2; s > 0; s >>= 1) {
        if (c < s) red[c] = fmaxf(red[c], red[c + s]);
        __syncthreads();
    }
    const float m = red[0];
    __syncthreads();

    const float e = sel ? expf(v - m) : 0.f;
    red[c] = e;
    __syncthreads();
    #pragma unroll
    for (int s = CHAN / 2; s > 0; s >>= 1) {
        if (c < s) red[c] += red[c + s];
        __syncthreads();
    }
    const float sum = red[0];

    gate[b * CHAN + c] = sel ? (e / sum) : 0.f;
}

// ---------------------------------------------------------------------------
// Kernel 3: out[b,c,:] = gate[b,c] * x[b,c,:]. One block per (b,c).
// Zero-gate channels (half!) skip the x read entirely and just store zeros.
// NT stores keep the write stream from evicting x from L3.
// ---------------------------------------------------------------------------
__global__ __launch_bounds__(256) void scale_kernel(const float* __restrict__ x,
                                                    const float* __restrict__ gate,
                                                    float* __restrict__ out) {
    const int bc = blockIdx.x;
    const float g = gate[bc];                 // uniform per block
    const float4v* xp = (const float4v*)(x + (size_t)bc * HW);
    float4v* op = (float4v*)(out + (size_t)bc * HW);
    const int t = threadIdx.x;

    if (g != 0.f) {
        #pragma unroll
        for (int i = t; i < HW / 4; i += 256) {
            float4v a = xp[i];
            a.x *= g; a.y *= g; a.z *= g; a.w *= g;
            __builtin_nontemporal_store(a, op + i);
        }
    } else {
        float4v z = {0.f, 0.f, 0.f, 0.f};
        #pragma unroll
        for (int i = t; i < HW / 4; i += 256) {
            __builtin_nontemporal_store(z, op + i);
        }
    }
}

extern "C" void kernel_launch(void* const* d_in, const int* in_sizes, int n_in,
                              void* d_out, int out_size, void* d_ws, size_t ws_size,
                              hipStream_t stream) {
    const float* x = (const float*)d_in[0];
    const float* y = (const float*)d_in[1];
    float* out = (float*)d_out;

    float* sims = (float*)d_ws;              // NBC floats
    float* gate = sims + NBC;                // NBC floats

    sim_kernel<<<NBC / 4, 256, 0, stream>>>(x, y, sims);
    gate_kernel<<<BATCH, CHAN, 0, stream>>>(sims, gate);
    scale_kernel<<<NBC, 256, 0, stream>>>(x, gate, out);
}